// Round 2
// baseline (348.752 us; speedup 1.0000x reference)
//
#include <hip/hip_runtime.h>
#include <cstdint>
#include <cstddef>

#define B_ROWS 16384
#define D_COLS 2048
#define NCLS   1000

// ---------------- Threefry-2x32 (JAX-compatible), host+device ----------------
__host__ __device__ __forceinline__ uint32_t rotl32(uint32_t v, int r) {
    return (v << r) | (v >> (32 - r));
}

__host__ __device__ inline void tf2x32(uint32_t k0, uint32_t k1,
                                       uint32_t x0, uint32_t x1,
                                       uint32_t& o0, uint32_t& o1) {
    uint32_t ks0 = k0, ks1 = k1, ks2 = k0 ^ k1 ^ 0x1BD11BDAu;
    x0 += ks0; x1 += ks1;
    x0 += x1; x1 = rotl32(x1, 13); x1 ^= x0;
    x0 += x1; x1 = rotl32(x1, 15); x1 ^= x0;
    x0 += x1; x1 = rotl32(x1, 26); x1 ^= x0;
    x0 += x1; x1 = rotl32(x1, 6);  x1 ^= x0;
    x0 += ks1; x1 += ks2 + 1u;
    x0 += x1; x1 = rotl32(x1, 17); x1 ^= x0;
    x0 += x1; x1 = rotl32(x1, 29); x1 ^= x0;
    x0 += x1; x1 = rotl32(x1, 16); x1 ^= x0;
    x0 += x1; x1 = rotl32(x1, 24); x1 ^= x0;
    x0 += ks2; x1 += ks0 + 2u;
    x0 += x1; x1 = rotl32(x1, 13); x1 ^= x0;
    x0 += x1; x1 = rotl32(x1, 15); x1 ^= x0;
    x0 += x1; x1 = rotl32(x1, 26); x1 ^= x0;
    x0 += x1; x1 = rotl32(x1, 6);  x1 ^= x0;
    x0 += ks0; x1 += ks1 + 3u;
    x0 += x1; x1 = rotl32(x1, 17); x1 ^= x0;
    x0 += x1; x1 = rotl32(x1, 29); x1 ^= x0;
    x0 += x1; x1 = rotl32(x1, 16); x1 ^= x0;
    x0 += x1; x1 = rotl32(x1, 24); x1 ^= x0;
    x0 += ks1; x1 += ks2 + 4u;
    x0 += x1; x1 = rotl32(x1, 13); x1 ^= x0;
    x0 += x1; x1 = rotl32(x1, 15); x1 ^= x0;
    x0 += x1; x1 = rotl32(x1, 26); x1 ^= x0;
    x0 += x1; x1 = rotl32(x1, 6);  x1 ^= x0;
    x0 += ks2; x1 += ks0 + 5u;
    o0 = x0; o1 = x1;
}

// XLA ErfInv (f32, Giles approximation)
__device__ __forceinline__ float erfinv_f(float x) {
    float w = -log1pf(-x * x);
    float p;
    if (w < 5.0f) {
        w -= 2.5f;
        p = 2.81022636e-08f;
        p = fmaf(p, w, 3.43273939e-07f);
        p = fmaf(p, w, -3.5233877e-06f);
        p = fmaf(p, w, -4.39150654e-06f);
        p = fmaf(p, w, 0.00021858087f);
        p = fmaf(p, w, -0.00125372503f);
        p = fmaf(p, w, -0.00417768164f);
        p = fmaf(p, w, 0.246640727f);
        p = fmaf(p, w, 1.50140941f);
    } else {
        w = sqrtf(w) - 3.0f;
        p = -0.000200214257f;
        p = fmaf(p, w, 0.000100950558f);
        p = fmaf(p, w, 0.00134934322f);
        p = fmaf(p, w, -0.00367342844f);
        p = fmaf(p, w, 0.00573950773f);
        p = fmaf(p, w, -0.0076224613f);
        p = fmaf(p, w, 0.00943887047f);
        p = fmaf(p, w, 1.00167406f);
        p = fmaf(p, w, 2.83297682f);
    }
    return p * x;
}

// ------------------------------- kernels -------------------------------------

__global__ void k_bits_hist(const int* __restrict__ y, int* __restrict__ cnt,
                            unsigned long long* __restrict__ kA,
                            unsigned long long* __restrict__ kB,
                            uint32_t s1_0, uint32_t s1_1,
                            uint32_t s2_0, uint32_t s2_1) {
    int i = blockIdx.x * 256 + threadIdx.x;
    atomicAdd(&cnt[y[i]], 1);
    uint32_t a, b;
    tf2x32(s1_0, s1_1, 0u, (uint32_t)i, a, b);
    kA[i] = ((unsigned long long)(a ^ b) << 14) | (unsigned)i;
    tf2x32(s2_0, s2_1, 0u, (uint32_t)i, a, b);
    kB[i] = ((unsigned long long)(a ^ b) << 14) | (unsigned)i;
}

__global__ void k_prefix(const int* __restrict__ cnt, int* __restrict__ rowstart) {
    __shared__ int sm[1024];
    int t = threadIdx.x;
    int v = (t < NCLS) ? cnt[t] : 0;
    sm[t] = v;
    for (int off = 1; off < 1024; off <<= 1) {
        __syncthreads();
        int u = (t >= off) ? sm[t - off] : 0;
        __syncthreads();
        sm[t] += u;
    }
    if (t < NCLS) rowstart[t] = sm[t] - v;
}

__global__ void k_scatter_rows(const int* __restrict__ y, const int* __restrict__ rowstart,
                               int* __restrict__ rowpos, int* __restrict__ rowlist) {
    int i = blockIdx.x * 256 + threadIdx.x;
    int c = y[i];
    int p = atomicAdd(&rowpos[c], 1);
    rowlist[rowstart[c] + p] = i;
}

// per-class sum/sumsq; grid (NCLS, 2): blockIdx.y picks a 1024-col half.
// 2-row manual unroll doubles loads in flight on the serial row chain.
__global__ void __launch_bounds__(256) k_class_sums(
        const float* __restrict__ x, const int* __restrict__ rowlist,
        const int* __restrict__ rowstart, const int* __restrict__ cnt,
        float* __restrict__ s, float* __restrict__ sq) {
    int c = blockIdx.x, h = blockIdx.y, t = threadIdx.x;
    int start = rowstart[c], n = cnt[c];
    const float4* xb = (const float4*)x + (size_t)h * 256 + t;
    float sx=0,sy=0,sz=0,sw=0, qx=0,qy=0,qz=0,qw=0;
    int r = 0;
    for (; r + 2 <= n; r += 2) {
        int row0 = rowlist[start + r];
        int row1 = rowlist[start + r + 1];
        float4 a = xb[(size_t)row0 * 512];
        float4 b = xb[(size_t)row1 * 512];
        sx += a.x; sy += a.y; sz += a.z; sw += a.w;
        qx = fmaf(a.x, a.x, qx); qy = fmaf(a.y, a.y, qy);
        qz = fmaf(a.z, a.z, qz); qw = fmaf(a.w, a.w, qw);
        sx += b.x; sy += b.y; sz += b.z; sw += b.w;
        qx = fmaf(b.x, b.x, qx); qy = fmaf(b.y, b.y, qy);
        qz = fmaf(b.z, b.z, qz); qw = fmaf(b.w, b.w, qw);
    }
    if (r < n) {
        int row = rowlist[start + r];
        float4 a = xb[(size_t)row * 512];
        sx += a.x; sy += a.y; sz += a.z; sw += a.w;
        qx = fmaf(a.x, a.x, qx); qy = fmaf(a.y, a.y, qy);
        qz = fmaf(a.z, a.z, qz); qw = fmaf(a.w, a.w, qw);
    }
    int o = c * 512 + h * 256 + t;
    ((float4*)s)[o]  = make_float4(sx, sy, sz, sw);
    ((float4*)sq)[o] = make_float4(qx, qy, qz, qw);
}

__global__ void k_noise(const float* __restrict__ s, const float* __restrict__ sq,
                        const int* __restrict__ cnt, float* __restrict__ noise,
                        uint32_t nk0, uint32_t nk1) {
    int n = blockIdx.x * 256 + threadIdx.x;       // < 2048000
    uint32_t b1, b2;
    tf2x32(nk0, nk1, 0u, (uint32_t)n, b1, b2);
    uint32_t bits = b1 ^ b2;
    float f = __uint_as_float((bits >> 9) | 0x3f800000u) - 1.0f;
    const float LO = -0.99999994f;
    float u = fmaxf(LO, fmaf(f, 2.0f, LO));
    float nr = 1.41421356f * erfinv_f(u);
    int c = n >> 11;
    float cf = (float)cnt[c];
    float m = s[n] / cf;
    float var = (sq[n] - cf * m * m) / (cf - 1.0f);
    float sd = sqrtf(fmaxf(var, 0.0f));
    noise[n] = fmaf(sd, nr, m);
}

// rank under stable ascending sort, both rounds; 2 i's per thread so one
// LDS broadcast read serves 2 compares. grid (32 i-tiles, 16 j-tiles).
__global__ void __launch_bounds__(256) k_rank12(
        const unsigned long long* __restrict__ kA,
        const unsigned long long* __restrict__ kB,
        int* __restrict__ rankA, int* __restrict__ rankB) {
    __shared__ unsigned long long sA[1024];
    __shared__ unsigned long long sB[1024];
    int t = threadIdx.x;
    int jbase = blockIdx.y * 1024;
    for (int k = t; k < 1024; k += 256) {
        sA[k] = kA[jbase + k];
        sB[k] = kB[jbase + k];
    }
    __syncthreads();
    int i0 = blockIdx.x * 512 + t;
    int i1 = i0 + 256;
    unsigned long long a0 = kA[i0], a1 = kA[i1];
    unsigned long long b0 = kB[i0], b1 = kB[i1];
    int ca0=0, ca1=0, cb0=0, cb1=0;
#pragma unroll 8
    for (int j = 0; j < 1024; j++) {
        unsigned long long sa = sA[j], sb = sB[j];
        ca0 += (sa < a0); ca1 += (sa < a1);
        cb0 += (sb < b0); cb1 += (sb < b1);
    }
    atomicAdd(&rankA[i0], ca0); atomicAdd(&rankA[i1], ca1);
    atomicAdd(&rankB[i0], cb0); atomicAdd(&rankB[i1], cb1);
}

__global__ void k_scatter1(const int* __restrict__ rank1, int* __restrict__ x1) {
    int i = blockIdx.x * 256 + threadIdx.x;
    x1[rank1[i]] = i;
}

__global__ void k_scatter2(const int* __restrict__ y, const int* __restrict__ x1,
                           const int* __restrict__ rank2, int* __restrict__ newY,
                           float* __restrict__ outTail) {
    int i = blockIdx.x * 256 + threadIdx.x;
    int v = y[x1[i]];
    int j = rank2[i];
    newY[j] = v;
    outTail[j] = (float)v;
}

__global__ void __launch_bounds__(256) k_final(
        const float* __restrict__ x, const float* __restrict__ noise,
        const int* __restrict__ newY, float* __restrict__ out) {
    int b = blockIdx.x, t = threadIdx.x;
    int ny = newY[b];
    const float4* xr = (const float4*)x + (size_t)b * (D_COLS / 4);
    const float4* nr = (const float4*)noise + (size_t)ny * (D_COLS / 4);
    float4* orow = (float4*)out + (size_t)b * (D_COLS / 4);
    float4 xa = xr[t], na = nr[t];
    float4 o;
    o.x = fmaf(0.1f, na.x, 0.9f * xa.x);
    o.y = fmaf(0.1f, na.y, 0.9f * xa.y);
    o.z = fmaf(0.1f, na.z, 0.9f * xa.z);
    o.w = fmaf(0.1f, na.w, 0.9f * xa.w);
    orow[t] = o;
    xa = xr[t + 256]; na = nr[t + 256];
    o.x = fmaf(0.1f, na.x, 0.9f * xa.x);
    o.y = fmaf(0.1f, na.y, 0.9f * xa.y);
    o.z = fmaf(0.1f, na.z, 0.9f * xa.z);
    o.w = fmaf(0.1f, na.w, 0.9f * xa.w);
    orow[t + 256] = o;
}

// ------------------------------- launcher ------------------------------------
extern "C" void kernel_launch(void* const* d_in, const int* in_sizes, int n_in,
                              void* d_out, int out_size, void* d_ws, size_t ws_size,
                              hipStream_t stream) {
    const float* x = (const float*)d_in[0];
    const int* y = (const int*)d_in[1];
    float* out = (float*)d_out;
    float* outTail = out + (size_t)B_ROWS * D_COLS;

    char* ws = (char*)d_ws;
    float* s     = (float*)(ws);
    float* sq    = (float*)(ws + 8192000);
    float* noise = (float*)(ws + 16384000);
    unsigned long long* kA = (unsigned long long*)(ws + 24576000);
    unsigned long long* kB = (unsigned long long*)(ws + 24707072);
    int* ints = (int*)(ws + 24838144);
    int* cnt      = ints;           // 1000
    int* rowpos   = ints + 1000;    // 1000
    int* rank1    = ints + 2000;    // 16384
    int* rank2    = ints + 18384;   // 16384
    int* rowstart = ints + 34768;   // 1000
    int* rowlist  = ints + 35768;   // 16384
    int* x1       = ints + 52152;   // 16384
    int* newY     = ints + 68536;   // 16384

    hipMemsetAsync(cnt, 0, 34768 * sizeof(int), stream);

    uint32_t nk0, nk1, pk0, pk1, pn0, pn1, s1_0, s1_1, s2_0, s2_1;
    tf2x32(0u, 42u, 0u, 0u, nk0, nk1);    // nk (noise key)
    tf2x32(0u, 42u, 0u, 1u, pk0, pk1);    // pk (perm key)
    tf2x32(pk0, pk1, 0u, 0u, pn0, pn1);   // pk after round-1 split
    tf2x32(pk0, pk1, 0u, 1u, s1_0, s1_1); // round-1 subkey
    tf2x32(pn0, pn1, 0u, 1u, s2_0, s2_1); // round-2 subkey

    k_bits_hist<<<64, 256, 0, stream>>>(y, cnt, kA, kB, s1_0, s1_1, s2_0, s2_1);
    k_prefix<<<1, 1024, 0, stream>>>(cnt, rowstart);
    k_scatter_rows<<<64, 256, 0, stream>>>(y, rowstart, rowpos, rowlist);
    k_class_sums<<<dim3(NCLS, 2), 256, 0, stream>>>(x, rowlist, rowstart, cnt, s, sq);
    k_noise<<<8000, 256, 0, stream>>>(s, sq, cnt, noise, nk0, nk1);
    k_rank12<<<dim3(32, 16), 256, 0, stream>>>(kA, kB, rank1, rank2);
    k_scatter1<<<64, 256, 0, stream>>>(rank1, x1);
    k_scatter2<<<64, 256, 0, stream>>>(y, x1, rank2, newY, outTail);
    k_final<<<16384, 256, 0, stream>>>(x, noise, newY, out);
}

// Round 3
// 322.797 us; speedup vs baseline: 1.0804x; 1.0804x over previous
//
#include <hip/hip_runtime.h>
#include <cstdint>
#include <cstddef>

#define B_ROWS 16384
#define D_COLS 2048
#define NCLS   1000
#define NBUCK  1024   // top-10-bit buckets for the shuffle rank sort

// ---------------- Threefry-2x32 (JAX-compatible), host+device ----------------
__host__ __device__ __forceinline__ uint32_t rotl32(uint32_t v, int r) {
    return (v << r) | (v >> (32 - r));
}

__host__ __device__ inline void tf2x32(uint32_t k0, uint32_t k1,
                                       uint32_t x0, uint32_t x1,
                                       uint32_t& o0, uint32_t& o1) {
    uint32_t ks0 = k0, ks1 = k1, ks2 = k0 ^ k1 ^ 0x1BD11BDAu;
    x0 += ks0; x1 += ks1;
    x0 += x1; x1 = rotl32(x1, 13); x1 ^= x0;
    x0 += x1; x1 = rotl32(x1, 15); x1 ^= x0;
    x0 += x1; x1 = rotl32(x1, 26); x1 ^= x0;
    x0 += x1; x1 = rotl32(x1, 6);  x1 ^= x0;
    x0 += ks1; x1 += ks2 + 1u;
    x0 += x1; x1 = rotl32(x1, 17); x1 ^= x0;
    x0 += x1; x1 = rotl32(x1, 29); x1 ^= x0;
    x0 += x1; x1 = rotl32(x1, 16); x1 ^= x0;
    x0 += x1; x1 = rotl32(x1, 24); x1 ^= x0;
    x0 += ks2; x1 += ks0 + 2u;
    x0 += x1; x1 = rotl32(x1, 13); x1 ^= x0;
    x0 += x1; x1 = rotl32(x1, 15); x1 ^= x0;
    x0 += x1; x1 = rotl32(x1, 26); x1 ^= x0;
    x0 += x1; x1 = rotl32(x1, 6);  x1 ^= x0;
    x0 += ks0; x1 += ks1 + 3u;
    x0 += x1; x1 = rotl32(x1, 17); x1 ^= x0;
    x0 += x1; x1 = rotl32(x1, 29); x1 ^= x0;
    x0 += x1; x1 = rotl32(x1, 16); x1 ^= x0;
    x0 += x1; x1 = rotl32(x1, 24); x1 ^= x0;
    x0 += ks1; x1 += ks2 + 4u;
    x0 += x1; x1 = rotl32(x1, 13); x1 ^= x0;
    x0 += x1; x1 = rotl32(x1, 15); x1 ^= x0;
    x0 += x1; x1 = rotl32(x1, 26); x1 ^= x0;
    x0 += x1; x1 = rotl32(x1, 6);  x1 ^= x0;
    x0 += ks2; x1 += ks0 + 5u;
    o0 = x0; o1 = x1;
}

// XLA ErfInv (f32, Giles approximation)
__device__ __forceinline__ float erfinv_f(float x) {
    float w = -log1pf(-x * x);
    float p;
    if (w < 5.0f) {
        w -= 2.5f;
        p = 2.81022636e-08f;
        p = fmaf(p, w, 3.43273939e-07f);
        p = fmaf(p, w, -3.5233877e-06f);
        p = fmaf(p, w, -4.39150654e-06f);
        p = fmaf(p, w, 0.00021858087f);
        p = fmaf(p, w, -0.00125372503f);
        p = fmaf(p, w, -0.00417768164f);
        p = fmaf(p, w, 0.246640727f);
        p = fmaf(p, w, 1.50140941f);
    } else {
        w = sqrtf(w) - 3.0f;
        p = -0.000200214257f;
        p = fmaf(p, w, 0.000100950558f);
        p = fmaf(p, w, 0.00134934322f);
        p = fmaf(p, w, -0.00367342844f);
        p = fmaf(p, w, 0.00573950773f);
        p = fmaf(p, w, -0.0076224613f);
        p = fmaf(p, w, 0.00943887047f);
        p = fmaf(p, w, 1.00167406f);
        p = fmaf(p, w, 2.83297682f);
    }
    return p * x;
}

// ------------------------------- kernels -------------------------------------

// y histogram + threefry bits for both shuffle rounds + bucket histograms.
__global__ void k_bits_hist(const int* __restrict__ y, int* __restrict__ cnt,
                            uint32_t* __restrict__ kAbits, uint32_t* __restrict__ kBbits,
                            int* __restrict__ bhA, int* __restrict__ bhB,
                            uint32_t s1_0, uint32_t s1_1,
                            uint32_t s2_0, uint32_t s2_1) {
    int i = blockIdx.x * 256 + threadIdx.x;
    atomicAdd(&cnt[y[i]], 1);
    uint32_t a, b;
    tf2x32(s1_0, s1_1, 0u, (uint32_t)i, a, b);
    uint32_t bitsA = a ^ b;
    kAbits[i] = bitsA;
    atomicAdd(&bhA[bitsA >> 22], 1);
    tf2x32(s2_0, s2_1, 0u, (uint32_t)i, a, b);
    uint32_t bitsB = a ^ b;
    kBbits[i] = bitsB;
    atomicAdd(&bhB[bitsB >> 22], 1);
}

// three independent 1024-wide exclusive prefix sums (cnt, bhA, bhB)
__global__ void k_prefix3(const int* __restrict__ cnt, int* __restrict__ rowstart,
                          const int* __restrict__ bhA, int* __restrict__ bsA,
                          const int* __restrict__ bhB, int* __restrict__ bsB) {
    __shared__ int sm[1024];
    int t = threadIdx.x;
    const int* src; int* dst; int n;
    if (blockIdx.x == 0)      { src = cnt; dst = rowstart; n = NCLS; }
    else if (blockIdx.x == 1) { src = bhA; dst = bsA;      n = NBUCK; }
    else                      { src = bhB; dst = bsB;      n = NBUCK; }
    int v = (t < n) ? src[t] : 0;
    sm[t] = v;
    for (int off = 1; off < 1024; off <<= 1) {
        __syncthreads();
        int u = (t >= off) ? sm[t - off] : 0;
        __syncthreads();
        sm[t] += u;
    }
    if (t < n) dst[t] = sm[t] - v;
}

// bucket rows by class + bucket indices by shuffle-key bucket (both rounds)
__global__ void k_scatter_all(const int* __restrict__ y,
                              const uint32_t* __restrict__ kAbits,
                              const uint32_t* __restrict__ kBbits,
                              const int* __restrict__ rowstart, int* __restrict__ rowpos,
                              int* __restrict__ rowlist,
                              const int* __restrict__ bsA, int* __restrict__ bposA,
                              int* __restrict__ memA,
                              const int* __restrict__ bsB, int* __restrict__ bposB,
                              int* __restrict__ memB) {
    int i = blockIdx.x * 256 + threadIdx.x;
    int c = y[i];
    int p = atomicAdd(&rowpos[c], 1);
    rowlist[rowstart[c] + p] = i;
    uint32_t bA = kAbits[i] >> 22;
    p = atomicAdd(&bposA[bA], 1);
    memA[bsA[bA] + p] = i;
    uint32_t bB = kBbits[i] >> 22;
    p = atomicAdd(&bposB[bB], 1);
    memB[bsB[bB] + p] = i;
}

// per-class sum/sumsq; grid (NCLS, 2): blockIdx.y picks a 1024-col half.
__global__ void __launch_bounds__(256) k_class_sums(
        const float* __restrict__ x, const int* __restrict__ rowlist,
        const int* __restrict__ rowstart, const int* __restrict__ cnt,
        float* __restrict__ s, float* __restrict__ sq) {
    int c = blockIdx.x, h = blockIdx.y, t = threadIdx.x;
    int start = rowstart[c], n = cnt[c];
    const float4* xb = (const float4*)x + (size_t)h * 256 + t;
    float sx=0,sy=0,sz=0,sw=0, qx=0,qy=0,qz=0,qw=0;
    int r = 0;
    for (; r + 2 <= n; r += 2) {
        int row0 = rowlist[start + r];
        int row1 = rowlist[start + r + 1];
        float4 a = xb[(size_t)row0 * 512];
        float4 b = xb[(size_t)row1 * 512];
        sx += a.x; sy += a.y; sz += a.z; sw += a.w;
        qx = fmaf(a.x, a.x, qx); qy = fmaf(a.y, a.y, qy);
        qz = fmaf(a.z, a.z, qz); qw = fmaf(a.w, a.w, qw);
        sx += b.x; sy += b.y; sz += b.z; sw += b.w;
        qx = fmaf(b.x, b.x, qx); qy = fmaf(b.y, b.y, qy);
        qz = fmaf(b.z, b.z, qz); qw = fmaf(b.w, b.w, qw);
    }
    if (r < n) {
        int row = rowlist[start + r];
        float4 a = xb[(size_t)row * 512];
        sx += a.x; sy += a.y; sz += a.z; sw += a.w;
        qx = fmaf(a.x, a.x, qx); qy = fmaf(a.y, a.y, qy);
        qz = fmaf(a.z, a.z, qz); qw = fmaf(a.w, a.w, qw);
    }
    int o = c * 512 + h * 256 + t;
    ((float4*)s)[o]  = make_float4(sx, sy, sz, sw);
    ((float4*)sq)[o] = make_float4(qx, qy, qz, qw);
}

__global__ void k_noise(const float* __restrict__ s, const float* __restrict__ sq,
                        const int* __restrict__ cnt, float* __restrict__ noise,
                        uint32_t nk0, uint32_t nk1) {
    int n = blockIdx.x * 256 + threadIdx.x;       // < 2048000
    uint32_t b1, b2;
    tf2x32(nk0, nk1, 0u, (uint32_t)n, b1, b2);
    uint32_t bits = b1 ^ b2;
    float f = __uint_as_float((bits >> 9) | 0x3f800000u) - 1.0f;
    const float LO = -0.99999994f;
    float u = fmaxf(LO, fmaf(f, 2.0f, LO));
    float nr = 1.41421356f * erfinv_f(u);
    int c = n >> 11;
    float cf = (float)cnt[c];
    float m = s[n] / cf;
    float var = (sq[n] - cf * m * m) / (cf - 1.0f);
    float sd = sqrtf(fmaxf(var, 0.0f));
    noise[n] = fmaf(sd, nr, m);
}

// bucketed rank for both rounds. Global rank = bucket_start + within-bucket
// rank (bucket = top 10 key bits, so bucket order == key order; ties broken
// by index == stable sort). Round 1's scatter (x1[rank]=i) fused in.
__global__ void k_rankAB(const uint32_t* __restrict__ kAbits,
                         const uint32_t* __restrict__ kBbits,
                         const int* __restrict__ bsA, const int* __restrict__ bhA,
                         const int* __restrict__ memA,
                         const int* __restrict__ bsB, const int* __restrict__ bhB,
                         const int* __restrict__ memB,
                         int* __restrict__ x1, int* __restrict__ rank2) {
    int i = blockIdx.x * 256 + threadIdx.x;
    uint32_t a = kAbits[i];
    {
        uint32_t b = a >> 22;
        int st = bsA[b], n = bhA[b];
        int ca = 0;
        for (int k = 0; k < n; k++) {
            int m = memA[st + k];
            uint32_t mb = kAbits[m];
            ca += (mb < a) || (mb == a && m < i);
        }
        x1[st + ca] = i;           // round-1 scatter fused (values were arange)
    }
    uint32_t c = kBbits[i];
    {
        uint32_t b = c >> 22;
        int st = bsB[b], n = bhB[b];
        int cb = 0;
        for (int k = 0; k < n; k++) {
            int m = memB[st + k];
            uint32_t mb = kBbits[m];
            cb += (mb < c) || (mb == c && m < i);
        }
        rank2[i] = st + cb;
    }
}

// round 2 scatter fused with gather: newY[rank2[i]] = y[x1[i]]; f32 tail of d_out
__global__ void k_scatter2(const int* __restrict__ y, const int* __restrict__ x1,
                           const int* __restrict__ rank2, int* __restrict__ newY,
                           float* __restrict__ outTail) {
    int i = blockIdx.x * 256 + threadIdx.x;
    int v = y[x1[i]];
    int j = rank2[i];
    newY[j] = v;
    outTail[j] = (float)v;
}

__global__ void __launch_bounds__(256) k_final(
        const float* __restrict__ x, const float* __restrict__ noise,
        const int* __restrict__ newY, float* __restrict__ out) {
    int b = blockIdx.x, t = threadIdx.x;
    int ny = newY[b];
    const float4* xr = (const float4*)x + (size_t)b * (D_COLS / 4);
    const float4* nr = (const float4*)noise + (size_t)ny * (D_COLS / 4);
    float4* orow = (float4*)out + (size_t)b * (D_COLS / 4);
    float4 xa = xr[t], na = nr[t];
    float4 o;
    o.x = fmaf(0.1f, na.x, 0.9f * xa.x);
    o.y = fmaf(0.1f, na.y, 0.9f * xa.y);
    o.z = fmaf(0.1f, na.z, 0.9f * xa.z);
    o.w = fmaf(0.1f, na.w, 0.9f * xa.w);
    orow[t] = o;
    xa = xr[t + 256]; na = nr[t + 256];
    o.x = fmaf(0.1f, na.x, 0.9f * xa.x);
    o.y = fmaf(0.1f, na.y, 0.9f * xa.y);
    o.z = fmaf(0.1f, na.z, 0.9f * xa.z);
    o.w = fmaf(0.1f, na.w, 0.9f * xa.w);
    orow[t + 256] = o;
}

// ------------------------------- launcher ------------------------------------
extern "C" void kernel_launch(void* const* d_in, const int* in_sizes, int n_in,
                              void* d_out, int out_size, void* d_ws, size_t ws_size,
                              hipStream_t stream) {
    const float* x = (const float*)d_in[0];
    const int* y = (const int*)d_in[1];
    float* out = (float*)d_out;
    float* outTail = out + (size_t)B_ROWS * D_COLS;

    char* ws = (char*)d_ws;
    float* s     = (float*)(ws);                       // 8,192,000 B
    float* sq    = (float*)(ws + 8192000);             // 8,192,000 B
    float* noise = (float*)(ws + 16384000);            // 8,192,000 B
    int* ints = (int*)(ws + 24576000);
    // --- zeroed region (one memset): 6096 ints ---
    int* cnt      = ints;            // 1000
    int* rowpos   = ints + 1000;     // 1000
    int* bhA      = ints + 2000;     // 1024
    int* bposA    = ints + 3024;     // 1024
    int* bhB      = ints + 4048;     // 1024
    int* bposB    = ints + 5072;     // 1024
    // --- non-zeroed ---
    int* rowstart = ints + 6096;     // 1000
    int* bsA      = ints + 7096;     // 1024
    int* bsB      = ints + 8120;     // 1024
    int* rowlist  = ints + 9144;     // 16384
    int* memA     = ints + 25528;    // 16384
    int* memB     = ints + 41912;    // 16384
    int* x1       = ints + 58296;    // 16384
    int* rank2    = ints + 74680;    // 16384
    int* newY     = ints + 91064;    // 16384
    uint32_t* kAbits = (uint32_t*)(ints + 107448);     // 16384
    uint32_t* kBbits = (uint32_t*)(ints + 123832);     // 16384

    hipMemsetAsync(cnt, 0, 6096 * sizeof(int), stream);

    // Host-side key derivation (jax.random.key(42), partitionable/foldlike split)
    uint32_t nk0, nk1, pk0, pk1, pn0, pn1, s1_0, s1_1, s2_0, s2_1;
    tf2x32(0u, 42u, 0u, 0u, nk0, nk1);    // nk (noise key)
    tf2x32(0u, 42u, 0u, 1u, pk0, pk1);    // pk (perm key)
    tf2x32(pk0, pk1, 0u, 0u, pn0, pn1);   // pk after round-1 split
    tf2x32(pk0, pk1, 0u, 1u, s1_0, s1_1); // round-1 subkey
    tf2x32(pn0, pn1, 0u, 1u, s2_0, s2_1); // round-2 subkey

    k_bits_hist<<<64, 256, 0, stream>>>(y, cnt, kAbits, kBbits, bhA, bhB,
                                        s1_0, s1_1, s2_0, s2_1);
    k_prefix3<<<3, 1024, 0, stream>>>(cnt, rowstart, bhA, bsA, bhB, bsB);
    k_scatter_all<<<64, 256, 0, stream>>>(y, kAbits, kBbits, rowstart, rowpos,
                                          rowlist, bsA, bposA, memA,
                                          bsB, bposB, memB);
    k_class_sums<<<dim3(NCLS, 2), 256, 0, stream>>>(x, rowlist, rowstart, cnt, s, sq);
    k_noise<<<8000, 256, 0, stream>>>(s, sq, cnt, noise, nk0, nk1);
    k_rankAB<<<64, 256, 0, stream>>>(kAbits, kBbits, bsA, bhA, memA,
                                     bsB, bhB, memB, x1, rank2);
    k_scatter2<<<64, 256, 0, stream>>>(y, x1, rank2, newY, outTail);
    k_final<<<16384, 256, 0, stream>>>(x, noise, newY, out);
}